// Round 4
// baseline (340.503 us; speedup 1.0000x reference)
//
#include <hip/hip_runtime.h>
#include <hip/hip_cooperative_groups.h>

// Softmax over 32M fp32: out = exp(x) / sum(exp(x))  (no max-subtraction, per reference)
//
// Single cooperative kernel, memory-bound:
//   Phase A: grid-stride float4 loads, per-thread exp-sum, wave64 shuffle + LDS
//            reduce, per-block partial -> d_ws[blockIdx].
//   grid.sync()
//   Phase B: each block reduces the GRID partials (4 KB, L2-hot), then grid-stride
//            float4 exp+scale with non-temporal stores (input stays L3-resident
//            from phase A, so the re-read hits Infinity Cache).
//
// GRID=1024 x BLOCK=256 -> 16 waves/CU: comfortably co-resident for cooperative
// launch (needs VGPR <= 128; kernel uses ~40) while still saturating HBM.

#define BLOCK 256
#define GRID 1024

typedef float vfloat4 __attribute__((ext_vector_type(4)));

namespace cg = cooperative_groups;

__global__ __launch_bounds__(BLOCK) void softmax_fused(
    const float* __restrict__ inp, float* __restrict__ out,
    float* __restrict__ partials, int n4) {
  const vfloat4* __restrict__ in4 = (const vfloat4*)inp;
  vfloat4* __restrict__ out4 = (vfloat4*)out;
  int tid = blockIdx.x * BLOCK + threadIdx.x;
  int stride = GRID * BLOCK;

  __shared__ float wsum[BLOCK / 64];

  // ---- Phase A: exp-sum ----
  float s0 = 0.0f, s1 = 0.0f;
  int i = tid;
  for (; i + stride < n4; i += 2 * stride) {
    vfloat4 a = in4[i];
    vfloat4 b = in4[i + stride];
    s0 += __expf(a.x) + __expf(a.y) + __expf(a.z) + __expf(a.w);
    s1 += __expf(b.x) + __expf(b.y) + __expf(b.z) + __expf(b.w);
  }
  for (; i < n4; i += stride) {
    vfloat4 a = in4[i];
    s0 += __expf(a.x) + __expf(a.y) + __expf(a.z) + __expf(a.w);
  }
  float s = s0 + s1;

  #pragma unroll
  for (int off = 32; off > 0; off >>= 1)
    s += __shfl_down(s, off, 64);

  if ((threadIdx.x & 63) == 0) wsum[threadIdx.x >> 6] = s;
  __syncthreads();
  if (threadIdx.x == 0)
    partials[blockIdx.x] = wsum[0] + wsum[1] + wsum[2] + wsum[3];

  cg::this_grid().sync();

  // ---- Phase B: reduce partials (4 KB, L2-hot), then scale ----
  float t = 0.0f;
  #pragma unroll
  for (int k = 0; k < GRID / BLOCK; ++k)
    t += partials[k * BLOCK + threadIdx.x];

  #pragma unroll
  for (int off = 32; off > 0; off >>= 1)
    t += __shfl_down(t, off, 64);

  if ((threadIdx.x & 63) == 0) wsum[threadIdx.x >> 6] = t;
  __syncthreads();
  float r = 1.0f / (wsum[0] + wsum[1] + wsum[2] + wsum[3]);

  i = tid;
  for (; i + stride < n4; i += 2 * stride) {
    vfloat4 a = in4[i];
    vfloat4 b = in4[i + stride];
    vfloat4 oa, ob;
    oa.x = __expf(a.x) * r; oa.y = __expf(a.y) * r;
    oa.z = __expf(a.z) * r; oa.w = __expf(a.w) * r;
    ob.x = __expf(b.x) * r; ob.y = __expf(b.y) * r;
    ob.z = __expf(b.z) * r; ob.w = __expf(b.w) * r;
    __builtin_nontemporal_store(oa, &out4[i]);
    __builtin_nontemporal_store(ob, &out4[i + stride]);
  }
  for (; i < n4; i += stride) {
    vfloat4 a = in4[i];
    vfloat4 oa;
    oa.x = __expf(a.x) * r; oa.y = __expf(a.y) * r;
    oa.z = __expf(a.z) * r; oa.w = __expf(a.w) * r;
    __builtin_nontemporal_store(oa, &out4[i]);
  }
}

extern "C" void kernel_launch(void* const* d_in, const int* in_sizes, int n_in,
                              void* d_out, int out_size, void* d_ws, size_t ws_size,
                              hipStream_t stream) {
  const float* inp = (const float*)d_in[0];
  float* out = (float*)d_out;
  float* partials = (float*)d_ws;  // GRID floats
  int n = in_sizes[0];
  int n4 = n >> 2;  // N = 2^25, divisible by 4

  void* args[] = {(void*)&inp, (void*)&out, (void*)&partials, (void*)&n4};
  hipLaunchCooperativeKernel((void*)softmax_fused, dim3(GRID), dim3(BLOCK),
                             args, 0, stream);
}